// Round 1
// baseline (232.555 us; speedup 1.0000x reference)
//
#include <hip/hip_runtime.h>
#include <cstdint>
#include <cstddef>

#define VOCAB 50000
#define EMBED 256
#define BATCH 16384
#define NSAMP 4096

typedef __bf16 bf16x8 __attribute__((ext_vector_type(8)));
typedef float f32x4 __attribute__((ext_vector_type(4)));

typedef __attribute__((address_space(3))) void lds_void_t;
typedef __attribute__((address_space(1))) void g_void_t;

// ---------- helpers ----------

__device__ __forceinline__ unsigned short f2bf(float f) {
    // RNE float -> bf16 (inputs are finite normals; no NaN handling needed)
    unsigned u = __float_as_uint(f);
    u += 0x7FFFu + ((u >> 16) & 1u);
    return (unsigned short)(u >> 16);
}

__device__ __forceinline__ float log_expected_count(int id) {
    // p = log1p(1/(id+1)) / log(VOCAB+1);  EC = -expm1(NSAMP * log1p(-p))
    float idf = (float)id;
    float p = log1pf(1.0f / (idf + 1.0f)) / logf((float)(VOCAB + 1));
    return __logf(-expm1f((float)NSAMP * log1pf(-p)));
}

__device__ __forceinline__ float softplus_f(float x) {
    // log(1+e^x), stable
    return fmaxf(x, 0.0f) + __logf(1.0f + __expf(-fabsf(x)));
}

// ---------- kernels ----------

__global__ void k_zero(double* acc) {
    if (threadIdx.x == 0 && blockIdx.x == 0) *acc = 0.0;
}

// One wave per sampled id: gather weight row -> bf16, compute adjusted bias.
__global__ __launch_bounds__(64) void k_prep_sampled(
        const int* __restrict__ sids, const float* __restrict__ W,
        const float* __restrict__ bias, unsigned short* __restrict__ Bbf,
        float* __restrict__ badj)
{
    int s = blockIdx.x;
    int lane = threadIdx.x;
    int sid = sids[s];
    float4 w = ((const float4*)(W + (size_t)sid * EMBED))[lane];
    ushort4 o;
    o.x = f2bf(w.x); o.y = f2bf(w.y); o.z = f2bf(w.z); o.w = f2bf(w.w);
    ((ushort4*)(Bbf + (size_t)s * EMBED))[lane] = o;
    if (lane == 0) badj[s] = bias[sid] - log_expected_count(sid);
}

// embedding fp32 -> bf16, one float4 per thread
__global__ __launch_bounds__(256) void k_convert_emb(
        const float* __restrict__ E, unsigned short* __restrict__ Ebf)
{
    int i = blockIdx.x * 256 + threadIdx.x;
    float4 v = ((const float4*)E)[i];
    ushort4 o;
    o.x = f2bf(v.x); o.y = f2bf(v.y); o.z = f2bf(v.z); o.w = f2bf(v.w);
    ((ushort4*)Ebf)[i] = o;
}

// True logits: one wave per batch row, fp32 dot, softplus(-tl), block atomic
__global__ __launch_bounds__(256) void k_true(
        const float* __restrict__ E, const int* __restrict__ tgt,
        const float* __restrict__ W, const float* __restrict__ bias,
        double* __restrict__ acc)
{
    int tid = threadIdx.x, wave = tid >> 6, lane = tid & 63;
    int b = blockIdx.x * 4 + wave;
    int label = tgt[b];
    float4 e = ((const float4*)(E + (size_t)b * EMBED))[lane];
    float4 w = ((const float4*)(W + (size_t)label * EMBED))[lane];
    float d = e.x * w.x + e.y * w.y + e.z * w.z + e.w * w.w;
    #pragma unroll
    for (int off = 32; off > 0; off >>= 1) d += __shfl_down(d, off, 64);
    __shared__ float ws[4];
    if (lane == 0) {
        float tl = d + bias[label] - log_expected_count(label);
        ws[wave] = softplus_f(-tl);
    }
    __syncthreads();
    if (tid == 0) atomicAdd(acc, (double)((ws[0] + ws[1]) + (ws[2] + ws[3])));
}

// Main fused GEMM: C[b,s] = Ebf[b,:].Bbf[s,:] ; sum softplus(C + badj[s]) -> acc
// 128x128 block tile, 4 waves (2x2), 64x64 wave tile, mfma 16x16x32 bf16, BK=32
__global__ __launch_bounds__(256) void k_gemm(
        const unsigned short* __restrict__ Ebf,
        const unsigned short* __restrict__ Bbf,
        const float* __restrict__ badj,
        double* __restrict__ acc)
{
    __shared__ __align__(16) unsigned short As[128 * 32]; // rows of 32 bf16 = 64B
    __shared__ __align__(16) unsigned short Bs[128 * 32];

    const int tid  = threadIdx.x;
    const int wave = tid >> 6;
    const int lane = tid & 63;
    const int bm0  = blockIdx.y * 128;
    const int bn0  = blockIdx.x * 128;
    const int wm   = (wave >> 1) * 64;
    const int wn   = (wave & 1) * 64;

    f32x4 acc4[4][4] = {};

    const int r_st = lane >> 2;        // row within 16-row chunk
    const int cb   = (lane & 3) * 16;  // byte offset within 64B k-row

    for (int k0 = 0; k0 < 256; k0 += 32) {
        __syncthreads();
        #pragma unroll
        for (int c = 0; c < 2; ++c) {
            int chunk = wave + c * 4;          // 8 chunks of 1KB per tile
            int row = chunk * 16 + r_st;
            const char* gA = (const char*)Ebf + ((size_t)(bm0 + row) * 256 + k0) * 2 + cb;
            const char* gB = (const char*)Bbf + ((size_t)(bn0 + row) * 256 + k0) * 2 + cb;
            // LDS dest is wave-uniform base + lane*16 by construction:
            // chunk*1024 + lane*16 == (chunk*16 + lane/4)*64 + (lane%4)*16
            char* lA = (char*)As + chunk * 1024 + lane * 16;
            char* lB = (char*)Bs + chunk * 1024 + lane * 16;
            __builtin_amdgcn_global_load_lds((g_void_t*)gA, (lds_void_t*)lA, 16, 0, 0);
            __builtin_amdgcn_global_load_lds((g_void_t*)gB, (lds_void_t*)lB, 16, 0, 0);
        }
        asm volatile("s_waitcnt vmcnt(0)" ::: "memory");
        __syncthreads();

        const int r16 = lane & 15;
        const int qb  = (lane >> 4) * 16;  // quad byte offset (k = quad*8 bf16)
        bf16x8 af[4], bfr[4];
        #pragma unroll
        for (int mi = 0; mi < 4; ++mi)
            af[mi] = *(const bf16x8*)((const char*)As + (wm + mi * 16 + r16) * 64 + qb);
        #pragma unroll
        for (int ni = 0; ni < 4; ++ni)
            bfr[ni] = *(const bf16x8*)((const char*)Bs + (wn + ni * 16 + r16) * 64 + qb);
        #pragma unroll
        for (int mi = 0; mi < 4; ++mi)
            #pragma unroll
            for (int ni = 0; ni < 4; ++ni)
                acc4[mi][ni] = __builtin_amdgcn_mfma_f32_16x16x32_bf16(
                    af[mi], bfr[ni], acc4[mi][ni], 0, 0, 0);
    }

    // Epilogue: logit = acc + badj[col]; sum softplus. C/D: col=lane&15, row=quad*4+r
    float lsum = 0.0f;
    const int r16 = lane & 15;
    #pragma unroll
    for (int ni = 0; ni < 4; ++ni) {
        float ba = badj[bn0 + wn + ni * 16 + r16];
        #pragma unroll
        for (int mi = 0; mi < 4; ++mi)
            #pragma unroll
            for (int r = 0; r < 4; ++r)
                lsum += softplus_f(acc4[mi][ni][r] + ba);
    }
    #pragma unroll
    for (int off = 32; off > 0; off >>= 1) lsum += __shfl_down(lsum, off, 64);
    __shared__ float wsum[4];
    if (lane == 0) wsum[wave] = lsum;
    __syncthreads();
    if (tid == 0) atomicAdd(acc, (double)((wsum[0] + wsum[1]) + (wsum[2] + wsum[3])));
}

__global__ void k_final(const double* __restrict__ acc, float* __restrict__ out) {
    if (threadIdx.x == 0 && blockIdx.x == 0)
        out[0] = (float)(*acc * (1.0 / (double)BATCH));
}

// ---------- launch ----------

extern "C" void kernel_launch(void* const* d_in, const int* in_sizes, int n_in,
                              void* d_out, int out_size, void* d_ws, size_t ws_size,
                              hipStream_t stream) {
    const float* emb  = (const float*)d_in[0];
    const int*   tgt  = (const int*)d_in[1];
    const int*   sids = (const int*)d_in[2];
    const float* W    = (const float*)d_in[3];
    const float* bias = (const float*)d_in[4];
    float* out = (float*)d_out;

    char* ws = (char*)d_ws;
    double*         acc  = (double*)ws;                                   // 8 B
    float*          badj = (float*)(ws + 256);                            // 16 KB
    unsigned short* Bbf  = (unsigned short*)(ws + 32768);                 // 2 MB
    unsigned short* Ebf  = (unsigned short*)(ws + 32768 + (size_t)NSAMP * EMBED * 2); // 8 MB

    hipLaunchKernelGGL(k_zero, dim3(1), dim3(64), 0, stream, acc);
    hipLaunchKernelGGL(k_prep_sampled, dim3(NSAMP), dim3(64), 0, stream,
                       sids, W, bias, Bbf, badj);
    hipLaunchKernelGGL(k_convert_emb, dim3(BATCH * EMBED / 4 / 256), dim3(256), 0, stream,
                       emb, Ebf);
    hipLaunchKernelGGL(k_true, dim3(BATCH / 4), dim3(256), 0, stream,
                       emb, tgt, W, bias, acc);
    hipLaunchKernelGGL(k_gemm, dim3(NSAMP / 128, BATCH / 128), dim3(256), 0, stream,
                       Ebf, Bbf, badj, acc);
    hipLaunchKernelGGL(k_final, dim3(1), dim3(64), 0, stream, acc, out);
}

// Round 2
// 162.665 us; speedup vs baseline: 1.4297x; 1.4297x over previous
//
#include <hip/hip_runtime.h>
#include <cstdint>
#include <cstddef>

#define VOCAB 50000
#define EMBED 256
#define BATCH 16384
#define NSAMP 4096

typedef __bf16 bf16x8 __attribute__((ext_vector_type(8)));
typedef float f32x4 __attribute__((ext_vector_type(4)));

typedef __attribute__((address_space(3))) void lds_void_t;
typedef __attribute__((address_space(1))) void g_void_t;

// ---------- helpers ----------

__device__ __forceinline__ unsigned short f2bf(float f) {
    unsigned u = __float_as_uint(f);
    u += 0x7FFFu + ((u >> 16) & 1u);
    return (unsigned short)(u >> 16);
}

__device__ __forceinline__ float log_expected_count(int id) {
    float idf = (float)id;
    float p = log1pf(1.0f / (idf + 1.0f)) / logf((float)(VOCAB + 1));
    return __logf(-expm1f((float)NSAMP * log1pf(-p)));
}

// softplus(x) = max(x,0) + log1p(e^{-|x|}); log1p via deg-5 minimax on [0,1]
// (A&S 4.1.43, |err| <= 1e-5). One trans-pipe op (exp) instead of exp+log.
__device__ __forceinline__ float softplus_f(float x) {
    float v = __expf(-fabsf(x));
    float p = fmaf(v, 0.03215845f, -0.13606275f);
    p = fmaf(v, p, 0.28947478f);
    p = fmaf(v, p, -0.49190896f);
    p = fmaf(v, p, 0.99949556f);
    return fmaxf(x, 0.0f) + v * p;
}

// ---------- kernels ----------

// Fused prep:
//  blocks [0, 4096):   true logits (1 wave = 1 batch row) + emb fp32->bf16 convert
//  blocks [4096,5120): sampled gather (1 wave = 1 sampled row) -> Bbf + badj
__global__ __launch_bounds__(256) void k_prep(
        const float* __restrict__ E, const int* __restrict__ tgt,
        const int* __restrict__ sids, const float* __restrict__ W,
        const float* __restrict__ bias,
        unsigned short* __restrict__ Ebf, unsigned short* __restrict__ Bbf,
        float* __restrict__ badj, double* __restrict__ pTrue)
{
    const int blk = blockIdx.x;
    const int tid = threadIdx.x, wave = tid >> 6, lane = tid & 63;

    if (blk < BATCH / 4) {
        int b = blk * 4 + wave;
        int label = tgt[b];
        float4 e = ((const float4*)(E + (size_t)b * EMBED))[lane];
        ushort4 o;
        o.x = f2bf(e.x); o.y = f2bf(e.y); o.z = f2bf(e.z); o.w = f2bf(e.w);
        ((ushort4*)(Ebf + (size_t)b * EMBED))[lane] = o;
        float4 w = ((const float4*)(W + (size_t)label * EMBED))[lane];
        float d = e.x * w.x + e.y * w.y + e.z * w.z + e.w * w.w;
        #pragma unroll
        for (int off = 32; off > 0; off >>= 1) d += __shfl_down(d, off, 64);
        __shared__ float ws[4];
        if (lane == 0) {
            float tl = d + bias[label] - log_expected_count(label);
            ws[wave] = softplus_f(-tl);
        }
        __syncthreads();
        if (tid == 0) pTrue[blk] = (double)((ws[0] + ws[1]) + (ws[2] + ws[3]));
    } else {
        int s = (blk - BATCH / 4) * 4 + wave;
        int sid = sids[s];
        float4 w = ((const float4*)(W + (size_t)sid * EMBED))[lane];
        ushort4 o;
        o.x = f2bf(w.x); o.y = f2bf(w.y); o.z = f2bf(w.z); o.w = f2bf(w.w);
        ((ushort4*)(Bbf + (size_t)s * EMBED))[lane] = o;
        if (lane == 0) badj[s] = bias[sid] - log_expected_count(sid);
    }
}

// Fused GEMM + softplus-sum.
// 128x128 block tile, 4 waves (2x2) of 64x64, mfma 16x16x32 bf16, BK=64.
// LDS rows are 128B (64 bf16); 16B chunks XOR-swizzled by (row&7) so both the
// global_load_lds staging (wave-uniform base + lane*16) and the ds_read_b128
// fragment reads are bank-conflict-free (8-cycle wave64 minimum).
__global__ __launch_bounds__(256) void k_gemm(
        const unsigned short* __restrict__ Ebf,
        const unsigned short* __restrict__ Bbf,
        const float* __restrict__ badj,
        double* __restrict__ pGemm)
{
    __shared__ __align__(16) unsigned short As[128 * 64]; // 16 KB
    __shared__ __align__(16) unsigned short Bs[128 * 64]; // 16 KB

    const int tid  = threadIdx.x;
    const int wave = tid >> 6;
    const int lane = tid & 63;
    const int bm0  = blockIdx.y * 128;
    const int bn0  = blockIdx.x * 128;
    const int wm   = (wave >> 1) * 64;
    const int wn   = (wave & 1) * 64;

    f32x4 acc4[4][4] = {};

    const int s_row = tid >> 3;   // row within 32-row staging group
    const int c_lds = tid & 7;    // LDS chunk position within 128B row

    for (int k0 = 0; k0 < 256; k0 += 64) {
        __syncthreads();
        #pragma unroll
        for (int i = 0; i < 4; ++i) {
            int row = i * 32 + s_row;
            int cg  = c_lds ^ (row & 7);   // global chunk this lane fetches
            const char* gA = (const char*)Ebf + ((size_t)(bm0 + row) * 256 + k0) * 2 + cg * 16;
            const char* gB = (const char*)Bbf + ((size_t)(bn0 + row) * 256 + k0) * 2 + cg * 16;
            char* lA = (char*)As + i * 4096 + wave * 1024 + lane * 16;
            char* lB = (char*)Bs + i * 4096 + wave * 1024 + lane * 16;
            __builtin_amdgcn_global_load_lds((g_void_t*)gA, (lds_void_t*)lA, 16, 0, 0);
            __builtin_amdgcn_global_load_lds((g_void_t*)gB, (lds_void_t*)lB, 16, 0, 0);
        }
        asm volatile("s_waitcnt vmcnt(0)" ::: "memory");
        __syncthreads();

        const int r16 = lane & 15;
        const int q   = lane >> 4;
        const int sw  = r16 & 7;
        #pragma unroll
        for (int ks = 0; ks < 2; ++ks) {
            bf16x8 af[4], bfr[4];
            const int kc = ks * 4 + q;         // 16B k-chunk index 0..7
            #pragma unroll
            for (int mi = 0; mi < 4; ++mi)
                af[mi] = *(const bf16x8*)((const char*)As
                          + (wm + mi * 16 + r16) * 128 + ((kc ^ sw) * 16));
            #pragma unroll
            for (int ni = 0; ni < 4; ++ni)
                bfr[ni] = *(const bf16x8*)((const char*)Bs
                          + (wn + ni * 16 + r16) * 128 + ((kc ^ sw) * 16));
            #pragma unroll
            for (int mi = 0; mi < 4; ++mi)
                #pragma unroll
                for (int ni = 0; ni < 4; ++ni)
                    acc4[mi][ni] = __builtin_amdgcn_mfma_f32_16x16x32_bf16(
                        af[mi], bfr[ni], acc4[mi][ni], 0, 0, 0);
        }
    }

    // Epilogue: C/D layout col=lane&15, row=quad*4+r
    float lsum = 0.0f;
    const int r16 = lane & 15;
    #pragma unroll
    for (int ni = 0; ni < 4; ++ni) {
        float ba = badj[bn0 + wn + ni * 16 + r16];
        #pragma unroll
        for (int mi = 0; mi < 4; ++mi)
            #pragma unroll
            for (int r = 0; r < 4; ++r)
                lsum += softplus_f(acc4[mi][ni][r] + ba);
    }
    #pragma unroll
    for (int off = 32; off > 0; off >>= 1) lsum += __shfl_down(lsum, off, 64);
    __shared__ float wsum[4];
    if (lane == 0) wsum[wave] = lsum;
    __syncthreads();
    if (tid == 0)
        pGemm[blockIdx.y * gridDim.x + blockIdx.x] =
            (double)((wsum[0] + wsum[1]) + (wsum[2] + wsum[3]));
}

// Reduce 8192 contiguous double partials (pTrue ++ pGemm), divide by BATCH.
__global__ __launch_bounds__(256) void k_final(
        const double* __restrict__ pAll, float* __restrict__ out)
{
    const int tid = threadIdx.x, wave = tid >> 6, lane = tid & 63;
    double s = 0.0;
    for (int i = tid; i < 8192; i += 256) s += pAll[i];
    #pragma unroll
    for (int off = 32; off > 0; off >>= 1) s += __shfl_down(s, off, 64);
    __shared__ double wsum[4];
    if (lane == 0) wsum[wave] = s;
    __syncthreads();
    if (tid == 0)
        out[0] = (float)(((wsum[0] + wsum[1]) + (wsum[2] + wsum[3]))
                         * (1.0 / (double)BATCH));
}

// ---------- launch ----------

extern "C" void kernel_launch(void* const* d_in, const int* in_sizes, int n_in,
                              void* d_out, int out_size, void* d_ws, size_t ws_size,
                              hipStream_t stream) {
    const float* emb  = (const float*)d_in[0];
    const int*   tgt  = (const int*)d_in[1];
    const int*   sids = (const int*)d_in[2];
    const float* W    = (const float*)d_in[3];
    const float* bias = (const float*)d_in[4];
    float* out = (float*)d_out;

    char* ws = (char*)d_ws;
    double*         pTrue = (double*)ws;                       // 4096 doubles
    double*         pGemm = (double*)(ws + 32768);             // 4096 doubles
    float*          badj  = (float*)(ws + 65536);              // 16 KB
    unsigned short* Bbf   = (unsigned short*)(ws + 131072);                          // 2 MB
    unsigned short* Ebf   = (unsigned short*)(ws + 131072 + (size_t)NSAMP * EMBED * 2); // 8 MB

    hipLaunchKernelGGL(k_prep, dim3(BATCH / 4 + NSAMP / 4), dim3(256), 0, stream,
                       emb, tgt, sids, W, bias, Ebf, Bbf, badj, pTrue);
    hipLaunchKernelGGL(k_gemm, dim3(NSAMP / 128, BATCH / 128), dim3(256), 0, stream,
                       Ebf, Bbf, badj, pGemm);
    hipLaunchKernelGGL(k_final, dim3(1), dim3(256), 0, stream,
                       (const double*)ws, out);
}

// Round 3
// 141.582 us; speedup vs baseline: 1.6425x; 1.1489x over previous
//
#include <hip/hip_runtime.h>
#include <cstdint>
#include <cstddef>

#define VOCAB 50000
#define EMBED 256
#define BATCH 16384
#define NSAMP 4096

typedef float f32x4 __attribute__((ext_vector_type(4)));
typedef int   i32x8 __attribute__((ext_vector_type(8)));

// ---------- helpers ----------

__device__ __forceinline__ float log_expected_count(int id) {
    float idf = (float)id;
    float p = log1pf(1.0f / (idf + 1.0f)) / logf((float)(VOCAB + 1));
    return __logf(-expm1f((float)NSAMP * log1pf(-p)));
}

// softplus(x) = max(x,0) + log1p(e^{-|x|}); deg-5 minimax (|err|<=1e-5)
__device__ __forceinline__ float softplus_f(float x) {
    float v = __expf(-fabsf(x));
    float p = fmaf(v, 0.03215845f, -0.13606275f);
    p = fmaf(v, p, 0.28947478f);
    p = fmaf(v, p, -0.49190896f);
    p = fmaf(v, p, 0.99949556f);
    return fmaxf(x, 0.0f) + v * p;
}

// pack 4 floats -> 4 fp8 e4m3 bytes (HW cvt, OCP on gfx950)
__device__ __forceinline__ int pk4_fp8(float a, float b, float c, float d) {
    int v = __builtin_amdgcn_cvt_pk_fp8_f32(a, b, 0, false);
    v = __builtin_amdgcn_cvt_pk_fp8_f32(c, d, v, true);
    return v;
}

// Fragment-order layout for an R x 256 fp8 matrix:
//   offset(row r, k) = (r>>4)*4096 + (k>>5)*512 + (r&15)*32 + (k&31)
// A wave's MFMA fragment (row-group g, k-step s) is the contiguous 2 KB at
// g*4096 + s*2048, per-lane at +lane*32 (lane&15 = row, lane>>4 = k-quad).

// ---------- kernels ----------

// blocks [0,1024): true logits + E -> fp8 fragment conversion (1 wave = 4 rows)
// blocks [1024,1088): gather W[sids] * 16 -> fp8 fragments + badj
__global__ __launch_bounds__(256) void k_prep(
        const float* __restrict__ E, const int* __restrict__ tgt,
        const int* __restrict__ sids, const float* __restrict__ W,
        const float* __restrict__ bias,
        unsigned char* __restrict__ EF, unsigned char* __restrict__ BF,
        float* __restrict__ badj, double* __restrict__ pTrue)
{
    const int blk = blockIdx.x, tid = threadIdx.x;
    const int wave = tid >> 6, lane = tid & 63;

    if (blk < 1024) {
        float tsum = 0.0f;
        #pragma unroll
        for (int i = 0; i < 4; ++i) {
            int b = (blk * 4 + wave) + 4096 * i;
            int label = tgt[b];
            float4 e  = ((const float4*)(E + (size_t)b * EMBED))[lane];
            float4 wv = ((const float4*)(W + (size_t)label * EMBED))[lane];
            int pk = pk4_fp8(e.x, e.y, e.z, e.w);
            *(int*)(EF + ((b >> 4) * 4096 + (lane >> 3) * 512
                          + (b & 15) * 32 + (lane & 7) * 4)) = pk;
            float d = e.x * wv.x + e.y * wv.y + e.z * wv.z + e.w * wv.w;
            #pragma unroll
            for (int off = 32; off > 0; off >>= 1) d += __shfl_down(d, off, 64);
            if (lane == 0) {
                float tl = d + bias[label] - log_expected_count(label);
                tsum += softplus_f(-tl);
            }
        }
        __shared__ float ts[4];
        if (lane == 0) ts[wave] = tsum;
        __syncthreads();
        if (tid == 0) pTrue[blk] = (double)((ts[0] + ts[1]) + (ts[2] + ts[3]));
    } else {
        #pragma unroll
        for (int i = 0; i < 4; ++i) {
            int task = (blk - 1024) * 256 + tid + 16384 * i;
            int s = task >> 4, p = task & 15;
            int sid = sids[s];
            const float4* wr = (const float4*)(W + (size_t)sid * EMBED + p * 16);
            float4 w0 = wr[0], w1 = wr[1], w2 = wr[2], w3 = wr[3];
            int4 o;
            o.x = pk4_fp8(w0.x * 16.0f, w0.y * 16.0f, w0.z * 16.0f, w0.w * 16.0f);
            o.y = pk4_fp8(w1.x * 16.0f, w1.y * 16.0f, w1.z * 16.0f, w1.w * 16.0f);
            o.z = pk4_fp8(w2.x * 16.0f, w2.y * 16.0f, w2.z * 16.0f, w2.w * 16.0f);
            o.w = pk4_fp8(w3.x * 16.0f, w3.y * 16.0f, w3.z * 16.0f, w3.w * 16.0f);
            *(int4*)(BF + ((s >> 4) * 4096 + (p >> 1) * 512
                           + (s & 15) * 32 + (p & 1) * 16)) = o;
            if (p == 0) badj[s] = bias[sid] - log_expected_count(sid);
        }
    }
}

// GEMM: direct-register MX-fp8, no LDS, no barriers in the hot path.
// Grid (32,128); block = 4 waves (2x2), each wave a 64x64 tile.
// Per wave: 32 x 32B coalesced fragment loads, 32 mfma_scale 16x16x128, epilogue.
__global__ __launch_bounds__(256, 2) void k_gemm(
        const unsigned char* __restrict__ EF,
        const unsigned char* __restrict__ BF,
        const float* __restrict__ badj,
        double* __restrict__ pGemm)
{
    const int tid  = threadIdx.x;
    const int wave = tid >> 6;
    const int lane = tid & 63;
    const int wm_g = blockIdx.y * 8 + (wave >> 1) * 4;  // A row-group base (16-row units)
    const int wn_g = blockIdx.x * 8 + (wave & 1) * 4;   // B row-group base

    i32x8 af[2][4], bf[2][4];
    #pragma unroll
    for (int s = 0; s < 2; ++s) {
        #pragma unroll
        for (int mi = 0; mi < 4; ++mi)
            af[s][mi] = *(const i32x8*)(EF + (size_t)(wm_g + mi) * 4096
                                        + s * 2048 + lane * 32);
        #pragma unroll
        for (int ni = 0; ni < 4; ++ni)
            bf[s][ni] = *(const i32x8*)(BF + (size_t)(wn_g + ni) * 4096
                                        + s * 2048 + lane * 32);
    }

    f32x4 acc[4][4] = {};
    #pragma unroll
    for (int s = 0; s < 2; ++s)
        #pragma unroll
        for (int mi = 0; mi < 4; ++mi)
            #pragma unroll
            for (int ni = 0; ni < 4; ++ni)
                acc[mi][ni] = __builtin_amdgcn_mfma_scale_f32_16x16x128_f8f6f4(
                    af[s][mi], bf[s][ni], acc[mi][ni],
                    0, 0,                       // cbsz=fp8(e4m3), blgp=fp8(e4m3)
                    0, 0x7F7F7F7F,              // scale A = 1.0 (E8M0 127)
                    0, 0x7F7F7F7F);             // scale B = 1.0

    // Epilogue: logit = acc/16 + badj[col]; C/D: col=lane&15, row=quad*4+r
    float lsum = 0.0f;
    const int r16 = lane & 15;
    #pragma unroll
    for (int ni = 0; ni < 4; ++ni) {
        float ba = badj[(wn_g + ni) * 16 + r16];
        #pragma unroll
        for (int mi = 0; mi < 4; ++mi)
            #pragma unroll
            for (int r = 0; r < 4; ++r)
                lsum += softplus_f(fmaf(acc[mi][ni][r], 0.0625f, ba));
    }
    #pragma unroll
    for (int off = 32; off > 0; off >>= 1) lsum += __shfl_down(lsum, off, 64);
    __shared__ float wsum[4];
    if (lane == 0) wsum[wave] = lsum;
    __syncthreads();
    if (tid == 0)
        pGemm[blockIdx.y * gridDim.x + blockIdx.x] =
            (double)((wsum[0] + wsum[1]) + (wsum[2] + wsum[3]));
}

__global__ __launch_bounds__(256) void k_final(
        const double* __restrict__ pTrue, const double* __restrict__ pGemm,
        float* __restrict__ out)
{
    const int tid = threadIdx.x, wave = tid >> 6, lane = tid & 63;
    double s = 0.0;
    for (int i = tid; i < 1024; i += 256) s += pTrue[i];
    for (int i = tid; i < 4096; i += 256) s += pGemm[i];
    #pragma unroll
    for (int off = 32; off > 0; off >>= 1) s += __shfl_down(s, off, 64);
    __shared__ double wsum[4];
    if (lane == 0) wsum[wave] = s;
    __syncthreads();
    if (tid == 0)
        out[0] = (float)(((wsum[0] + wsum[1]) + (wsum[2] + wsum[3]))
                         * (1.0 / (double)BATCH));
}

// ---------- launch ----------

extern "C" void kernel_launch(void* const* d_in, const int* in_sizes, int n_in,
                              void* d_out, int out_size, void* d_ws, size_t ws_size,
                              hipStream_t stream) {
    const float* emb  = (const float*)d_in[0];
    const int*   tgt  = (const int*)d_in[1];
    const int*   sids = (const int*)d_in[2];
    const float* W    = (const float*)d_in[3];
    const float* bias = (const float*)d_in[4];
    float* out = (float*)d_out;

    char* ws = (char*)d_ws;
    double*        pTrue = (double*)ws;                        // 1024 doubles
    double*        pGemm = (double*)(ws + 8192);               // 4096 doubles
    float*         badj  = (float*)(ws + 40960);               // 16 KB
    unsigned char* BF    = (unsigned char*)(ws + 57344);       // 1 MB
    unsigned char* EF    = (unsigned char*)(ws + 57344 + 1048576); // 4 MB

    hipLaunchKernelGGL(k_prep, dim3(1088), dim3(256), 0, stream,
                       emb, tgt, sids, W, bias, EF, BF, badj, pTrue);
    hipLaunchKernelGGL(k_gemm, dim3(32, 128), dim3(256), 0, stream,
                       EF, BF, badj, pGemm);
    hipLaunchKernelGGL(k_final, dim3(1), dim3(256), 0, stream,
                       pTrue, pGemm, out);
}